// Round 4
// baseline (291.059 us; speedup 1.0000x reference)
//
#include <hip/hip_runtime.h>
#include <hip/hip_bf16.h>
#include <math.h>

#define NH 12
#define DH 64
#define SL 1024
#define NB 8
#define ED 768
#define NTAP 2047
#define NF 33
#define NSEQ 2048

typedef __attribute__((ext_vector_type(8))) short bf16x8;
typedef __attribute__((ext_vector_type(4))) float f32x4;

#define GLB_U32(p) ((const __attribute__((address_space(1))) unsigned int*)(p))
#define LDS_U32(p) ((__attribute__((address_space(3))) unsigned int*)(p))

__device__ __forceinline__ float2 cadd(float2 a, float2 b){ return make_float2(a.x+b.x, a.y+b.y); }
__device__ __forceinline__ float2 csub(float2 a, float2 b){ return make_float2(a.x-b.x, a.y-b.y); }
__device__ __forceinline__ float2 cmul(float2 a, float2 b){ return make_float2(a.x*b.x - a.y*b.y, a.x*b.y + a.y*b.x); }

__device__ __forceinline__ unsigned short bf16bits(float f) {
    __hip_bfloat16 hb = __float2bfloat16(f);
    return *reinterpret_cast<unsigned short*>(&hb);
}
__device__ __forceinline__ float bf16val(unsigned short u) {
    __hip_bfloat16 hb = *reinterpret_cast<__hip_bfloat16*>(&u);
    return __bfloat162float(hb);
}
__device__ __forceinline__ void cvt8(const float* v, bf16x8& h8, bf16x8& l8) {
    #pragma unroll
    for (int j = 0; j < 8; ++j) {
        unsigned short hb = bf16bits(v[j]);
        h8[j] = (short)hb;
        l8[j] = (short)bf16bits(v[j] - bf16val(hb));
    }
}

// ---------------- Stockham FFT pieces (N=2048 = 8*8*8*4, constant geometry) ----------------
// pad to break power-of-2 LDS strides
#define FPAD(i) ((i) + ((i) >> 3))

// 4-pt DFT, natural order in/out. DIR=-1 fwd (W=e^{-2pi i/4}), +1 inv.
template<int DIR>
__device__ __forceinline__ void dft4v(float2 v[4]) {
    float2 e0 = cadd(v[0], v[2]), e1 = csub(v[0], v[2]);
    float2 o0 = cadd(v[1], v[3]), o1 = csub(v[1], v[3]);
    float2 o1t = (DIR < 0) ? make_float2(o1.y, -o1.x) : make_float2(-o1.y, o1.x);
    v[0] = cadd(e0, o0);
    v[1] = cadd(e1, o1t);
    v[2] = csub(e0, o0);
    v[3] = csub(e1, o1t);
}

template<int DIR>
__device__ __forceinline__ void dft8v(float2 v[8]) {
    const float RS = 0.70710678118654752440f;
    float2 e[4] = { v[0], v[2], v[4], v[6] };
    float2 o[4] = { v[1], v[3], v[5], v[7] };
    dft4v<DIR>(e);
    dft4v<DIR>(o);
    // twiddles W8^k on o[k]
    float2 t1 = (DIR < 0) ? make_float2(RS * (o[1].x + o[1].y), RS * (o[1].y - o[1].x))
                          : make_float2(RS * (o[1].x - o[1].y), RS * (o[1].y + o[1].x));
    float2 t2 = (DIR < 0) ? make_float2(o[2].y, -o[2].x) : make_float2(-o[2].y, o[2].x);
    float2 t3 = (DIR < 0) ? make_float2(RS * (o[3].y - o[3].x), RS * (-o[3].x - o[3].y))
                          : make_float2(RS * (-o[3].x - o[3].y), RS * (o[3].x - o[3].y));
    v[0] = cadd(e[0], o[0]); v[4] = csub(e[0], o[0]);
    v[1] = cadd(e[1], t1);   v[5] = csub(e[1], t1);
    v[2] = cadd(e[2], t2);   v[6] = csub(e[2], t2);
    v[3] = cadd(e[3], t3);   v[7] = csub(e[3], t3);
}

// One Stockham stage: read src[j + (2048/R)*r], twiddle W_{R*L}^{k*r} (power-chain from
// LUT twd[c*k], c = 2048/(R*L)), DFT-R, write dst[(j/L)*R*L + k + L*r].
template<int DIR, int L, int R>
__device__ __forceinline__ void fft_stage(const float* __restrict__ sr, const float* __restrict__ si,
                                          float* __restrict__ dr, float* __restrict__ di,
                                          const float2* __restrict__ twd, int tid) {
    const int T = 2048 / R;
    #pragma unroll
    for (int jj = 0; jj < T; jj += 256) {
        int j = tid + jj;
        int k = j & (L - 1);
        int blk = j / L;
        float2 v[R];
        #pragma unroll
        for (int r = 0; r < R; ++r) {
            int idx = FPAD(j + T * r);
            v[r] = make_float2(sr[idx], si[idx]);
        }
        if (L > 1) {
            const int c = 2048 / (R * L);
            float2 w1 = twd[c * k];
            if (DIR > 0) w1.y = -w1.y;
            float2 w = w1;
            v[1] = cmul(v[1], w);
            #pragma unroll
            for (int r = 2; r < R; ++r) { w = cmul(w, w1); v[r] = cmul(v[r], w); }
        }
        if (R == 8) dft8v<DIR>(v); else dft4v<DIR>(v);
        int base = blk * (R * L) + k;
        #pragma unroll
        for (int r = 0; r < R; ++r) {
            int idx = FPAD(base + L * r);
            dr[idx] = v[r].x; di[idx] = v[r].y;
        }
    }
}

// ktw: twiddle table W_2048^i, i<512
__global__ void ktw(float2* __restrict__ twg) {
    int i = blockIdx.x * 256 + threadIdx.x;
    if (i < 512) {
        float ang = -6.28318530717958647692f * (float)i / 2048.0f;
        twg[i] = make_float2(cosf(ang), sinf(ang));
    }
}

// K1: coalesced 2-pass online softmax. grid (NH*2): (h, e-half of 32). 256 thr = 8 s-rows x 32 e.
__global__ void k1_softmax(const float* __restrict__ tp, float* __restrict__ psf_out) {
    __shared__ float ms[8][33], ss[8][33];
    int h = blockIdx.x >> 1, e0 = (blockIdx.x & 1) * 32;
    int tid = threadIdx.x;
    int srow = tid >> 5, e = tid & 31;
    const float* base = tp + (size_t)h * NTAP * 64 + e0 + e;
    float m = -1e30f, s = 0.f;
    for (int st = srow; st < NTAP; st += 8) {
        float v = base[(size_t)st * 64];
        float mn = fmaxf(m, v);
        s = s * expf(m - mn) + expf(v - mn);
        m = mn;
    }
    ms[srow][e] = m; ss[srow][e] = s;
    __syncthreads();
    if (srow == 0) {
        float M = ms[0][e], S = ss[0][e];
        #pragma unroll
        for (int i = 1; i < 8; ++i) {
            float mi = ms[i][e], si = ss[i][e];
            float mn = fmaxf(M, mi);
            S = S * expf(M - mn) + si * expf(mi - mn);
            M = mn;
        }
        ms[0][e] = M; ss[0][e] = 1.0f / S;
    }
    __syncthreads();
    float M = ms[0][e], inv = ss[0][e];
    float* ob = psf_out + (size_t)h * NTAP * 64 + e0 + e;
    for (int st = srow; st < NTAP; st += 8) {
        float v = base[(size_t)st * 64];
        float o = (st < SL) ? expf(v - M) * inv : 0.0f;
        ob[(size_t)st * 64] = o;
    }
}

// K2: channel DFT-64 (forward, f=0..32) of masked psf; output Pc[h][f][s] (s<1024).
__global__ void k2_psf_cdft(const float* __restrict__ psf, float2* __restrict__ Pc) {
    __shared__ float p[64][65];
    __shared__ float2 tw[64];
    int s0 = blockIdx.x * 64;
    int h = blockIdx.y;
    for (int i = threadIdx.x; i < 64; i += 256) {
        float ang = 6.28318530717958647692f * (float)i / 64.0f;
        tw[i] = make_float2(cosf(ang), sinf(ang));
    }
    for (int i = threadIdx.x; i < 4096; i += 256) {
        int sl = i >> 6, e = i & 63;
        p[sl][e] = psf[((size_t)h * NTAP + (s0 + sl)) * 64 + e];
    }
    __syncthreads();
    for (int o = threadIdx.x; o < NF * 64; o += 256) {
        int f = o >> 6, sl = o & 63;
        float re = 0.f, im = 0.f;
        for (int e = 0; e < 64; ++e) {
            int m = (e * f) & 63;
            float v = p[sl][e];
            re += v * tw[m].x;
            im -= v * tw[m].y;
        }
        Pc[(size_t)(h * NF + f) * SL + (s0 + sl)] = make_float2(re, im);
    }
}

// K3: seq FFT-2048 of psf per (h,f), Stockham, natural order out.
__global__ __launch_bounds__(256) void k3_psf_fft(const float2* __restrict__ Pc, float2* __restrict__ Pf,
                                                  const float2* __restrict__ twg) {
    __shared__ float Ar[2304], Ai[2304], Br[2304], Bi[2304];
    __shared__ float2 twd[512];
    int h = blockIdx.x / NF, f = blockIdx.x % NF;
    int tid = threadIdx.x;
    for (int i = tid; i < 512; i += 256) twd[i] = twg[i];
    const float2* src = Pc + (size_t)(h * NF + f) * SL;
    // S1 fwd fused with global load (L=1,R=8): writes A[8*tid + r]
    {
        float2 v[8];
        #pragma unroll
        for (int r = 0; r < 4; ++r) v[r] = src[tid + 256 * r];
        #pragma unroll
        for (int r = 4; r < 8; ++r) v[r] = make_float2(0.f, 0.f);
        dft8v<-1>(v);
        #pragma unroll
        for (int r = 0; r < 8; ++r) {
            int idx = FPAD(tid * 8 + r);
            Ar[idx] = v[r].x; Ai[idx] = v[r].y;
        }
    }
    __syncthreads();
    fft_stage<-1, 8, 8>(Ar, Ai, Br, Bi, twd, tid);  __syncthreads();
    fft_stage<-1, 64, 8>(Br, Bi, Ar, Ai, twd, tid); __syncthreads();
    // S4 (L=512,R=4) fused with global store: out[j + 512*r] natural
    float2* dst = Pf + (size_t)(h * NF + f) * NSEQ;
    #pragma unroll
    for (int jj = 0; jj < 512; jj += 256) {
        int j = tid + jj;
        float2 v[4];
        #pragma unroll
        for (int r = 0; r < 4; ++r) {
            int idx = FPAD(j + 512 * r);
            v[r] = make_float2(Ar[idx], Ai[idx]);
        }
        float2 w1 = twd[j >= 512 ? 0 : j];  // j<512 always
        float2 w = w1;
        v[1] = cmul(v[1], w);
        w = cmul(w, w1); v[2] = cmul(v[2], w);
        w = cmul(w, w1); v[3] = cmul(v[3], w);
        dft4v<-1>(v);
        #pragma unroll
        for (int r = 0; r < 4; ++r) dst[j + 512 * r] = v[r];
    }
}

// K4m: channel DFT-64 as split-bf16 MFMA. (unchanged)
__global__ __launch_bounds__(256) void k4_mfma(const float* __restrict__ emb,
                                               float* __restrict__ XcRe, float* __restrict__ XcIm) {
    __shared__ union {
        struct { float Emb[128][65]; float Cm[80][65]; } s;
        float Dl[66][133];
    } u;
    const int t0 = blockIdx.x * 128;
    const int bh = blockIdx.y;
    const int b = bh / NH, h = bh % NH;
    const int tid = threadIdx.x, lane = tid & 63, w = tid >> 6;

    for (int i = tid; i < 128 * 16; i += 256) {
        int r = i >> 4, q = i & 15;
        float4 v = *(const float4*)&emb[((size_t)b * SL + t0 + r) * ED + h * 64 + q * 4];
        u.s.Emb[r][q * 4 + 0] = v.x; u.s.Emb[r][q * 4 + 1] = v.y;
        u.s.Emb[r][q * 4 + 2] = v.z; u.s.Emb[r][q * 4 + 3] = v.w;
    }
    for (int i = tid; i < 80 * 64; i += 256) {
        int c = i >> 6, e = i & 63;
        float val = 0.f;
        if (c < 33) {
            int m = (c * e) & 63;
            val = cosf(0.09817477042468103870f * (float)m);
        } else if (c < 66) {
            int m = ((c - 33) * e) & 63;
            val = -sinf(0.09817477042468103870f * (float)m);
        }
        u.s.Cm[c][e] = val;
    }
    __syncthreads();

    f32x4 acc[2][5] = {};
    const int lr = lane & 15, lg = lane >> 4;
    #pragma unroll
    for (int ks = 0; ks < 64; ks += 32) {
        const int kg = ks + lg * 8;
        bf16x8 bh8[5], bl8[5];
        #pragma unroll
        for (int n = 0; n < 5; ++n) {
            float bv[8];
            #pragma unroll
            for (int j = 0; j < 8; ++j) bv[j] = u.s.Cm[n * 16 + lr][kg + j];
            cvt8(bv, bh8[n], bl8[n]);
        }
        #pragma unroll
        for (int m = 0; m < 2; ++m) {
            float av[8];
            const int row = w * 32 + m * 16 + lr;
            #pragma unroll
            for (int j = 0; j < 8; ++j) av[j] = u.s.Emb[row][kg + j];
            bf16x8 ah8, al8;
            cvt8(av, ah8, al8);
            #pragma unroll
            for (int n = 0; n < 5; ++n) {
                acc[m][n] = __builtin_amdgcn_mfma_f32_16x16x32_bf16(ah8, bh8[n], acc[m][n], 0, 0, 0);
                acc[m][n] = __builtin_amdgcn_mfma_f32_16x16x32_bf16(ah8, bl8[n], acc[m][n], 0, 0, 0);
                acc[m][n] = __builtin_amdgcn_mfma_f32_16x16x32_bf16(al8, bh8[n], acc[m][n], 0, 0, 0);
            }
        }
    }
    __syncthreads();
    #pragma unroll
    for (int n = 0; n < 5; ++n) {
        int c = n * 16 + lr;
        if (c < 66) {
            #pragma unroll
            for (int m = 0; m < 2; ++m)
                #pragma unroll
                for (int j = 0; j < 4; ++j)
                    u.Dl[c][w * 32 + m * 16 + lg * 4 + j] = acc[m][n][j];
        }
    }
    __syncthreads();
    for (int i = tid; i < 66 * 128; i += 256) {
        int c = i >> 7, t = i & 127;
        float val = u.Dl[c][t];
        if (c < 33) XcRe[(size_t)(bh * NF + c) * SL + t0 + t] = val;
        else        XcIm[(size_t)(bh * NF + (c - 33)) * SL + t0 + t] = val;
    }
}

// K5: Stockham fwd FFT -> pointwise * Pf -> Stockham inv FFT, in-place on Xc planes.
__global__ __launch_bounds__(256) void k5_seq_conv(float* __restrict__ XcRe, float* __restrict__ XcIm,
                                                   const float2* __restrict__ Pf,
                                                   const float2* __restrict__ twg) {
    __shared__ float Ar[2304], Ai[2304], Br[2304], Bi[2304];
    __shared__ float2 twd[512];
    int f = blockIdx.x % NF;
    int bh = blockIdx.x / NF;
    int h = bh % NH;
    int tid = threadIdx.x;
    for (int i = tid; i < 512; i += 256) twd[i] = twg[i];
    float* xre = XcRe + (size_t)(bh * NF + f) * SL;
    float* xim = XcIm + (size_t)(bh * NF + f) * SL;
    // S1 fwd fused global load
    {
        float2 v[8];
        #pragma unroll
        for (int r = 0; r < 4; ++r) v[r] = make_float2(xre[tid + 256 * r], xim[tid + 256 * r]);
        #pragma unroll
        for (int r = 4; r < 8; ++r) v[r] = make_float2(0.f, 0.f);
        dft8v<-1>(v);
        #pragma unroll
        for (int r = 0; r < 8; ++r) {
            int idx = FPAD(tid * 8 + r);
            Ar[idx] = v[r].x; Ai[idx] = v[r].y;
        }
    }
    __syncthreads();
    fft_stage<-1, 8, 8>(Ar, Ai, Br, Bi, twd, tid);   __syncthreads();
    fft_stage<-1, 64, 8>(Br, Bi, Ar, Ai, twd, tid);  __syncthreads();
    fft_stage<-1, 512, 4>(Ar, Ai, Br, Bi, twd, tid); __syncthreads();
    // pointwise multiply (natural order), in-place in B
    const float2* pf = Pf + (size_t)(h * NF + f) * NSEQ;
    #pragma unroll
    for (int q = 0; q < 8; ++q) {
        int i = tid + 256 * q;
        int idx = FPAD(i);
        float2 a = make_float2(Br[idx], Bi[idx]);
        float2 p = cmul(a, pf[i]);
        Br[idx] = p.x; Bi[idx] = p.y;
    }
    __syncthreads();
    // inverse
    fft_stage<1, 1, 8>(Br, Bi, Ar, Ai, twd, tid);  __syncthreads();
    fft_stage<1, 8, 8>(Ar, Ai, Br, Bi, twd, tid);  __syncthreads();
    fft_stage<1, 64, 8>(Br, Bi, Ar, Ai, twd, tid); __syncthreads();
    // S4 inverse (L=512,R=4) fused store, keep t<1024 (r=0,1), scale 1/2048
    const float sc = 1.0f / 2048.0f;
    #pragma unroll
    for (int jj = 0; jj < 512; jj += 256) {
        int j = tid + jj;
        float2 v[4];
        #pragma unroll
        for (int r = 0; r < 4; ++r) {
            int idx = FPAD(j + 512 * r);
            v[r] = make_float2(Ar[idx], Ai[idx]);
        }
        float2 w1 = twd[j];
        w1.y = -w1.y;
        float2 w = w1;
        v[1] = cmul(v[1], w);
        w = cmul(w, w1); v[2] = cmul(v[2], w);
        w = cmul(w, w1); v[3] = cmul(v[3], w);
        dft4v<1>(v);
        xre[j] = v[0].x * sc;        xim[j] = v[0].y * sc;
        xre[j + 512] = v[1].x * sc;  xim[j + 512] = v[1].y * sc;
    }
}

// K6m: inverse channel DFT-64 as split-bf16 MFMA + exact GELU. (unchanged)
__global__ __launch_bounds__(256) void k6_mfma(const float* __restrict__ XcRe,
                                               const float* __restrict__ XcIm,
                                               ushort* __restrict__ Gh, ushort* __restrict__ Gl) {
    __shared__ float Ys[64][133];
    __shared__ float Cm[64][65];
    const int t0 = blockIdx.x * 128;
    const int bh = blockIdx.y;
    const int b = bh / NH, h = bh % NH;
    const int tid = threadIdx.x, lane = tid & 63, w = tid >> 6;

    for (int i = tid; i < 64 * 32; i += 256) {
        int c = i >> 5, tq = i & 31;
        const float* src = (c < 33) ? XcRe + (size_t)(bh * NF + c) * SL
                                    : XcIm + (size_t)(bh * NF + (c - 32)) * SL;
        float4 v = *(const float4*)&src[t0 + tq * 4];
        Ys[c][tq * 4 + 0] = v.x; Ys[c][tq * 4 + 1] = v.y;
        Ys[c][tq * 4 + 2] = v.z; Ys[c][tq * 4 + 3] = v.w;
    }
    for (int i = tid; i < 64 * 64; i += 256) {
        int e = i >> 6, c = i & 63;
        float v;
        if (c <= 32) {
            int m = (c * e) & 63;
            float wt = (c == 0 || c == 32) ? (1.0f / 64.0f) : (2.0f / 64.0f);
            v = wt * cosf(0.09817477042468103870f * (float)m);
        } else {
            int m = ((c - 32) * e) & 63;
            v = -(2.0f / 64.0f) * sinf(0.09817477042468103870f * (float)m);
        }
        Cm[e][c] = v;
    }
    __syncthreads();

    f32x4 acc[2][4] = {};
    const int lr = lane & 15, lg = lane >> 4;
    #pragma unroll
    for (int ks = 0; ks < 64; ks += 32) {
        const int kg = ks + lg * 8;
        bf16x8 bh8[4], bl8[4];
        #pragma unroll
        for (int n = 0; n < 4; ++n) {
            float bv[8];
            #pragma unroll
            for (int j = 0; j < 8; ++j) bv[j] = Cm[n * 16 + lr][kg + j];
            cvt8(bv, bh8[n], bl8[n]);
        }
        #pragma unroll
        for (int m = 0; m < 2; ++m) {
            const int row = w * 32 + m * 16 + lr;
            float av[8];
            #pragma unroll
            for (int j = 0; j < 8; ++j) av[j] = Ys[kg + j][row];
            bf16x8 ah8, al8;
            cvt8(av, ah8, al8);
            #pragma unroll
            for (int n = 0; n < 4; ++n) {
                acc[m][n] = __builtin_amdgcn_mfma_f32_16x16x32_bf16(ah8, bh8[n], acc[m][n], 0, 0, 0);
                acc[m][n] = __builtin_amdgcn_mfma_f32_16x16x32_bf16(ah8, bl8[n], acc[m][n], 0, 0, 0);
                acc[m][n] = __builtin_amdgcn_mfma_f32_16x16x32_bf16(al8, bh8[n], acc[m][n], 0, 0, 0);
            }
        }
    }
    #pragma unroll
    for (int n = 0; n < 4; ++n) {
        const int col = h * 64 + n * 16 + lr;
        #pragma unroll
        for (int m = 0; m < 2; ++m) {
            #pragma unroll
            for (int j = 0; j < 4; ++j) {
                int t = t0 + w * 32 + m * 16 + lg * 4 + j;
                float v = acc[m][n][j];
                float g = 0.5f * v * (1.0f + erff(v * 0.70710678118654752440f));
                size_t idx = ((size_t)b * SL + t) * ED + col;
                unsigned short hb = bf16bits(g);
                Gh[idx] = hb;
                Gl[idx] = bf16bits(g - bf16val(hb));
            }
        }
    }
}

// K0b: cast W to bf16 hi/lo pair.
__global__ void k0_castW(const float* __restrict__ W,
                         ushort* __restrict__ Wh, ushort* __restrict__ Wl) {
    int i = blockIdx.x * 256 + threadIdx.x;
    if (i < ED * ED) {
        float w = W[i];
        unsigned short hb = bf16bits(w);
        Wh[i] = hb;
        Wl[i] = bf16bits(w - bf16val(hb));
    }
}

// K7: projection GEMM via split-bf16 MFMA. (unchanged)
__global__ __launch_bounds__(256) void k7_mfma(
        const ushort* __restrict__ Gh, const ushort* __restrict__ Gl,
        const ushort* __restrict__ Wh, const ushort* __restrict__ Wl,
        const float* __restrict__ bias, float* __restrict__ out) {
    __shared__ ushort Ah[128 * 32], Al[128 * 32], Bh[128 * 32], Bl[128 * 32];
    const int j0 = blockIdx.x * 128;
    const int i0 = blockIdx.y * 128;
    const int tid = threadIdx.x;
    const int lane = tid & 63, wid = tid >> 6;
    const int wm = wid >> 1, wn = wid & 1;

    const int stRow = wid * 32 + (lane >> 2);
    const int stCol = (lane & 3) * 8;
    const int ldsBase0 = wid * 1024;
    const int ldsBase1 = wid * 1024 + 512;

    f32x4 acc[4][4] = {};

    const int arow = wm * 64 + (lane & 15);
    const int brow = wn * 64 + (lane & 15);
    const int kb8  = (lane >> 4) * 8;

    for (int k0 = 0; k0 < ED; k0 += 32) {
        const ushort* gA = Gh + (size_t)(i0 + stRow) * ED + k0 + stCol;
        const ushort* gAl = Gl + (size_t)(i0 + stRow) * ED + k0 + stCol;
        const ushort* gB = Wh + (size_t)(j0 + stRow) * ED + k0 + stCol;
        const ushort* gBl = Wl + (size_t)(j0 + stRow) * ED + k0 + stCol;
        __builtin_amdgcn_global_load_lds(GLB_U32(gA), LDS_U32(&Ah[ldsBase0]), 16, 0, 0);
        __builtin_amdgcn_global_load_lds(GLB_U32(gA + 16 * ED), LDS_U32(&Ah[ldsBase1]), 16, 0, 0);
        __builtin_amdgcn_global_load_lds(GLB_U32(gAl), LDS_U32(&Al[ldsBase0]), 16, 0, 0);
        __builtin_amdgcn_global_load_lds(GLB_U32(gAl + 16 * ED), LDS_U32(&Al[ldsBase1]), 16, 0, 0);
        __builtin_amdgcn_global_load_lds(GLB_U32(gB), LDS_U32(&Bh[ldsBase0]), 16, 0, 0);
        __builtin_amdgcn_global_load_lds(GLB_U32(gB + 16 * ED), LDS_U32(&Bh[ldsBase1]), 16, 0, 0);
        __builtin_amdgcn_global_load_lds(GLB_U32(gBl), LDS_U32(&Bl[ldsBase0]), 16, 0, 0);
        __builtin_amdgcn_global_load_lds(GLB_U32(gBl + 16 * ED), LDS_U32(&Bl[ldsBase1]), 16, 0, 0);
        __syncthreads();

        bf16x8 ah[4], al[4], bh[4], bl[4];
        #pragma unroll
        for (int m = 0; m < 4; ++m) {
            ah[m] = *(const bf16x8*)&Ah[(arow + m * 16) * 32 + kb8];
            al[m] = *(const bf16x8*)&Al[(arow + m * 16) * 32 + kb8];
        }
        #pragma unroll
        for (int n = 0; n < 4; ++n) {
            bh[n] = *(const bf16x8*)&Bh[(brow + n * 16) * 32 + kb8];
            bl[n] = *(const bf16x8*)&Bl[(brow + n * 16) * 32 + kb8];
        }
        #pragma unroll
        for (int m = 0; m < 4; ++m)
            #pragma unroll
            for (int n = 0; n < 4; ++n) {
                acc[m][n] = __builtin_amdgcn_mfma_f32_16x16x32_bf16(ah[m], bh[n], acc[m][n], 0, 0, 0);
                acc[m][n] = __builtin_amdgcn_mfma_f32_16x16x32_bf16(ah[m], bl[n], acc[m][n], 0, 0, 0);
                acc[m][n] = __builtin_amdgcn_mfma_f32_16x16x32_bf16(al[m], bh[n], acc[m][n], 0, 0, 0);
            }
        __syncthreads();
    }

    const int ocol0 = j0 + wn * 64 + (lane & 15);
    const int orow0 = i0 + wm * 64 + (lane >> 4) * 4;
    #pragma unroll
    for (int n = 0; n < 4; ++n) {
        const float bv = bias[ocol0 + n * 16];
        #pragma unroll
        for (int m = 0; m < 4; ++m) {
            #pragma unroll
            for (int j = 0; j < 4; ++j) {
                out[(size_t)(orow0 + m * 16 + j) * ED + ocol0 + n * 16] = acc[m][n][j] + bv;
            }
        }
    }
}

extern "C" void kernel_launch(void* const* d_in, const int* in_sizes, int n_in,
                              void* d_out, int out_size, void* d_ws, size_t ws_size,
                              hipStream_t stream) {
    (void)in_sizes; (void)n_in; (void)out_size; (void)ws_size;
    const float* emb  = (const float*)d_in[0];   // [8,1024,768]
    const float* tp   = (const float*)d_in[1];   // [12,2047,64]
    const float* W    = (const float*)d_in[2];   // [768,768]
    const float* bias = (const float*)d_in[3];   // [768]

    float* out_conv = (float*)d_out;                             // 8*1024*768
    float* out_psf  = out_conv + (size_t)NB * SL * ED;           // 12*2047*64

    // workspace layout:
    float2* Pc = (float2*)d_ws;                                  // 12*33*1024 complex (dead after k3)
    float2* Pf = Pc + (size_t)NH * NF * SL;                      // 12*33*2048 complex
    float*  XcRe = (float*)(Pf + (size_t)NH * NF * NSEQ);        // 96*33*1024 f32
    float*  XcIm = XcRe + (size_t)NB * NH * NF * SL;             // 96*33*1024 f32
    ushort* Gh = (ushort*)(XcIm + (size_t)NB * NH * NF * SL);    // 8192*768 bf16
    ushort* Gl = Gh + (size_t)NB * SL * ED;                      // 8192*768 bf16
    // W hi/lo overlaid on Pc region (2.36 MB <= 3.24 MB)
    ushort* Whh = (ushort*)Pc;
    ushort* Wll = Whh + (size_t)ED * ED;
    // twiddle table overlaid on Gh start (4 KB): written first, consumed by k3/k5 before k6 writes Gh
    float2* twg = (float2*)Gh;

    ktw<<<dim3(2), dim3(256), 0, stream>>>(twg);
    k1_softmax<<<dim3(NH * 2), dim3(256), 0, stream>>>(tp, out_psf);
    k2_psf_cdft<<<dim3(SL / 64, NH), dim3(256), 0, stream>>>(out_psf, Pc);
    k3_psf_fft<<<dim3(NH * NF), dim3(256), 0, stream>>>(Pc, Pf, twg);
    k0_castW<<<dim3((ED * ED + 255) / 256), dim3(256), 0, stream>>>(W, Whh, Wll);
    k4_mfma<<<dim3(SL / 128, NB * NH), dim3(256), 0, stream>>>(emb, XcRe, XcIm);
    k5_seq_conv<<<dim3(NB * NH * NF), dim3(256), 0, stream>>>(XcRe, XcIm, Pf, twg);
    k6_mfma<<<dim3(SL / 128, NB * NH), dim3(256), 0, stream>>>(XcRe, XcIm, Gh, Gl);
    k7_mfma<<<dim3(ED / 128, (NB * SL) / 128), dim3(256), 0, stream>>>(
        Gh, Gl, Whh, Wll, bias, out_conv);
}

// Round 5
// 188.291 us; speedup vs baseline: 1.5458x; 1.5458x over previous
//
#include <hip/hip_runtime.h>
#include <hip/hip_bf16.h>
#include <math.h>

#define NH 12
#define DH 64
#define SL 1024
#define NB 8
#define ED 768
#define NTAP 2047
#define NF 33
#define NSEQ 2048

typedef __attribute__((ext_vector_type(8))) short bf16x8;
typedef __attribute__((ext_vector_type(4))) float f32x4;

#define GLB_U32(p) ((const __attribute__((address_space(1))) unsigned int*)(p))
#define LDS_U32(p) ((__attribute__((address_space(3))) unsigned int*)(p))

__device__ __forceinline__ float2 cadd(float2 a, float2 b){ return make_float2(a.x+b.x, a.y+b.y); }
__device__ __forceinline__ float2 csub(float2 a, float2 b){ return make_float2(a.x-b.x, a.y-b.y); }
__device__ __forceinline__ float2 cmul(float2 a, float2 b){ return make_float2(a.x*b.x - a.y*b.y, a.x*b.y + a.y*b.x); }

__device__ __forceinline__ unsigned short bf16bits(float f) {
    __hip_bfloat16 hb = __float2bfloat16(f);
    return *reinterpret_cast<unsigned short*>(&hb);
}
__device__ __forceinline__ float bf16val(unsigned short u) {
    __hip_bfloat16 hb = *reinterpret_cast<__hip_bfloat16*>(&u);
    return __bfloat162float(hb);
}
__device__ __forceinline__ void cvt8(const float* v, bf16x8& h8, bf16x8& l8) {
    #pragma unroll
    for (int j = 0; j < 8; ++j) {
        unsigned short hb = bf16bits(v[j]);
        h8[j] = (short)hb;
        l8[j] = (short)bf16bits(v[j] - bf16val(hb));
    }
}

// ---------------- Stockham FFT pieces (N=2048 = 8*8*8*4, constant geometry) ----------------
#define FPAD(i) ((i) + ((i) >> 3))

template<int DIR>
__device__ __forceinline__ void dft4v(float2 v[4]) {
    float2 e0 = cadd(v[0], v[2]), e1 = csub(v[0], v[2]);
    float2 o0 = cadd(v[1], v[3]), o1 = csub(v[1], v[3]);
    float2 o1t = (DIR < 0) ? make_float2(o1.y, -o1.x) : make_float2(-o1.y, o1.x);
    v[0] = cadd(e0, o0);
    v[1] = cadd(e1, o1t);
    v[2] = csub(e0, o0);
    v[3] = csub(e1, o1t);
}

template<int DIR>
__device__ __forceinline__ void dft8v(float2 v[8]) {
    const float RS = 0.70710678118654752440f;
    float2 e[4] = { v[0], v[2], v[4], v[6] };
    float2 o[4] = { v[1], v[3], v[5], v[7] };
    dft4v<DIR>(e);
    dft4v<DIR>(o);
    float2 t1 = (DIR < 0) ? make_float2(RS * (o[1].x + o[1].y), RS * (o[1].y - o[1].x))
                          : make_float2(RS * (o[1].x - o[1].y), RS * (o[1].y + o[1].x));
    float2 t2 = (DIR < 0) ? make_float2(o[2].y, -o[2].x) : make_float2(-o[2].y, o[2].x);
    float2 t3 = (DIR < 0) ? make_float2(RS * (o[3].y - o[3].x), RS * (-o[3].x - o[3].y))
                          : make_float2(RS * (-o[3].x - o[3].y), RS * (o[3].x - o[3].y));
    v[0] = cadd(e[0], o[0]); v[4] = csub(e[0], o[0]);
    v[1] = cadd(e[1], t1);   v[5] = csub(e[1], t1);
    v[2] = cadd(e[2], t2);   v[6] = csub(e[2], t2);
    v[3] = cadd(e[3], t3);   v[7] = csub(e[3], t3);
}

template<int DIR, int L, int R>
__device__ __forceinline__ void fft_stage(const float* __restrict__ sr, const float* __restrict__ si,
                                          float* __restrict__ dr, float* __restrict__ di,
                                          const float2* __restrict__ twd, int tid) {
    const int T = 2048 / R;
    #pragma unroll
    for (int jj = 0; jj < T; jj += 256) {
        int j = tid + jj;
        int k = j & (L - 1);
        int blk = j / L;
        float2 v[R];
        #pragma unroll
        for (int r = 0; r < R; ++r) {
            int idx = FPAD(j + T * r);
            v[r] = make_float2(sr[idx], si[idx]);
        }
        if (L > 1) {
            const int c = 2048 / (R * L);
            float2 w1 = twd[c * k];
            if (DIR > 0) w1.y = -w1.y;
            float2 w = w1;
            v[1] = cmul(v[1], w);
            #pragma unroll
            for (int r = 2; r < R; ++r) { w = cmul(w, w1); v[r] = cmul(v[r], w); }
        }
        if (R == 8) dft8v<DIR>(v); else dft4v<DIR>(v);
        int base = blk * (R * L) + k;
        #pragma unroll
        for (int r = 0; r < R; ++r) {
            int idx = FPAD(base + L * r);
            dr[idx] = v[r].x; di[idx] = v[r].y;
        }
    }
}

// ktw: twiddle table W_2048^i, i<512
__global__ void ktw(float2* __restrict__ twg) {
    int i = blockIdx.x * 256 + threadIdx.x;
    if (i < 512) {
        float ang = -6.28318530717958647692f * (float)i / 2048.0f;
        twg[i] = make_float2(cosf(ang), sinf(ang));
    }
}

// ---------------- K1: 3-pass coalesced softmax over taps ----------------
// k1a: per (h, chunk of 64 rows): online (max,sum) partials per e.
__global__ void k1a_partial(const float* __restrict__ tp, float* __restrict__ pMax, float* __restrict__ pSum) {
    __shared__ float lm[4][64], ls[4][64];
    int c = blockIdx.x, h = blockIdx.y;
    int tid = threadIdx.x, w = tid >> 6, e = tid & 63;
    const float* base = tp + (size_t)h * NTAP * 64;
    float m = -1e30f, s = 0.f;
    #pragma unroll
    for (int i = 0; i < 16; ++i) {
        int row = c * 64 + w + 4 * i;
        if (row < NTAP) {
            float v = base[(size_t)row * 64 + e];
            float mn = fmaxf(m, v);
            s = s * expf(m - mn) + expf(v - mn);
            m = mn;
        }
    }
    lm[w][e] = m; ls[w][e] = s;
    __syncthreads();
    if (w == 0) {
        float M = m, S = s;
        #pragma unroll
        for (int i = 1; i < 4; ++i) {
            float mi = lm[i][e], si = ls[i][e];
            float mn = fmaxf(M, mi);
            S = S * expf(M - mn) + si * expf(mi - mn);
            M = mn;
        }
        pMax[(h * 32 + c) * 64 + e] = M;
        pSum[(h * 32 + c) * 64 + e] = S;
    }
}

// k1b: fold 32 chunk partials -> M, 1/S per (h,e)
__global__ void k1b_fold(const float* __restrict__ pMax, const float* __restrict__ pSum,
                         float* __restrict__ Mf, float* __restrict__ Invf) {
    int h = blockIdx.x, e = threadIdx.x;
    float M = -1e30f, S = 0.f;
    for (int c = 0; c < 32; ++c) {
        float mi = pMax[(h * 32 + c) * 64 + e], si = pSum[(h * 32 + c) * 64 + e];
        float mn = fmaxf(M, mi);
        S = S * expf(M - mn) + si * expf(mi - mn);
        M = mn;
    }
    Mf[h * 64 + e] = M;
    Invf[h * 64 + e] = 1.0f / S;
}

// k1c: normalize + causal mask; rows >= SL store zero without loading.
__global__ void k1c_norm(const float* __restrict__ tp, const float* __restrict__ Mf,
                         const float* __restrict__ Invf, float* __restrict__ psf_out) {
    int c = blockIdx.x, h = blockIdx.y;
    int tid = threadIdx.x, w = tid >> 6, e = tid & 63;
    float M = Mf[h * 64 + e], inv = Invf[h * 64 + e];
    const float* base = tp + (size_t)h * NTAP * 64;
    float* ob = psf_out + (size_t)h * NTAP * 64;
    #pragma unroll
    for (int i = 0; i < 16; ++i) {
        int row = c * 64 + w + 4 * i;
        if (row < NTAP) {
            float o = 0.f;
            if (row < SL) o = expf(base[(size_t)row * 64 + e] - M) * inv;
            ob[(size_t)row * 64 + e] = o;
        }
    }
}

// K2: channel DFT-64 (forward, f=0..32) of masked psf; output Pc[h][f][s] (s<1024).
__global__ void k2_psf_cdft(const float* __restrict__ psf, float2* __restrict__ Pc) {
    __shared__ float p[64][65];
    __shared__ float2 tw[64];
    int s0 = blockIdx.x * 64;
    int h = blockIdx.y;
    for (int i = threadIdx.x; i < 64; i += 256) {
        float ang = 6.28318530717958647692f * (float)i / 64.0f;
        tw[i] = make_float2(cosf(ang), sinf(ang));
    }
    for (int i = threadIdx.x; i < 4096; i += 256) {
        int sl = i >> 6, e = i & 63;
        p[sl][e] = psf[((size_t)h * NTAP + (s0 + sl)) * 64 + e];
    }
    __syncthreads();
    for (int o = threadIdx.x; o < NF * 64; o += 256) {
        int f = o >> 6, sl = o & 63;
        float re = 0.f, im = 0.f;
        for (int e = 0; e < 64; ++e) {
            int m = (e * f) & 63;
            float v = p[sl][e];
            re += v * tw[m].x;
            im -= v * tw[m].y;
        }
        Pc[(size_t)(h * NF + f) * SL + (s0 + sl)] = make_float2(re, im);
    }
}

// K3: seq FFT-2048 of psf per (h,f), Stockham, natural order out.
__global__ __launch_bounds__(256) void k3_psf_fft(const float2* __restrict__ Pc, float2* __restrict__ Pf,
                                                  const float2* __restrict__ twg) {
    __shared__ float Ar[2304], Ai[2304], Br[2304], Bi[2304];
    __shared__ float2 twd[512];
    int h = blockIdx.x / NF, f = blockIdx.x % NF;
    int tid = threadIdx.x;
    for (int i = tid; i < 512; i += 256) twd[i] = twg[i];
    const float2* src = Pc + (size_t)(h * NF + f) * SL;
    {
        float2 v[8];
        #pragma unroll
        for (int r = 0; r < 4; ++r) v[r] = src[tid + 256 * r];
        #pragma unroll
        for (int r = 4; r < 8; ++r) v[r] = make_float2(0.f, 0.f);
        dft8v<-1>(v);
        #pragma unroll
        for (int r = 0; r < 8; ++r) {
            int idx = FPAD(tid * 8 + r);
            Ar[idx] = v[r].x; Ai[idx] = v[r].y;
        }
    }
    __syncthreads();
    fft_stage<-1, 8, 8>(Ar, Ai, Br, Bi, twd, tid);  __syncthreads();
    fft_stage<-1, 64, 8>(Br, Bi, Ar, Ai, twd, tid); __syncthreads();
    float2* dst = Pf + (size_t)(h * NF + f) * NSEQ;
    #pragma unroll
    for (int jj = 0; jj < 512; jj += 256) {
        int j = tid + jj;
        float2 v[4];
        #pragma unroll
        for (int r = 0; r < 4; ++r) {
            int idx = FPAD(j + 512 * r);
            v[r] = make_float2(Ar[idx], Ai[idx]);
        }
        float2 w1 = twd[j];
        float2 w = w1;
        v[1] = cmul(v[1], w);
        w = cmul(w, w1); v[2] = cmul(v[2], w);
        w = cmul(w, w1); v[3] = cmul(v[3], w);
        dft4v<-1>(v);
        #pragma unroll
        for (int r = 0; r < 4; ++r) dst[j + 512 * r] = v[r];
    }
}

// K4m: channel DFT-64 as split-bf16 MFMA.
__global__ __launch_bounds__(256) void k4_mfma(const float* __restrict__ emb,
                                               float* __restrict__ XcRe, float* __restrict__ XcIm) {
    __shared__ union {
        struct { float Emb[128][65]; float Cm[80][65]; } s;
        float Dl[66][133];
    } u;
    const int t0 = blockIdx.x * 128;
    const int bh = blockIdx.y;
    const int b = bh / NH, h = bh % NH;
    const int tid = threadIdx.x, lane = tid & 63, w = tid >> 6;

    for (int i = tid; i < 128 * 16; i += 256) {
        int r = i >> 4, q = i & 15;
        float4 v = *(const float4*)&emb[((size_t)b * SL + t0 + r) * ED + h * 64 + q * 4];
        u.s.Emb[r][q * 4 + 0] = v.x; u.s.Emb[r][q * 4 + 1] = v.y;
        u.s.Emb[r][q * 4 + 2] = v.z; u.s.Emb[r][q * 4 + 3] = v.w;
    }
    for (int i = tid; i < 80 * 64; i += 256) {
        int c = i >> 6, e = i & 63;
        float val = 0.f;
        if (c < 33) {
            int m = (c * e) & 63;
            val = cosf(0.09817477042468103870f * (float)m);
        } else if (c < 66) {
            int m = ((c - 33) * e) & 63;
            val = -sinf(0.09817477042468103870f * (float)m);
        }
        u.s.Cm[c][e] = val;
    }
    __syncthreads();

    f32x4 acc[2][5] = {};
    const int lr = lane & 15, lg = lane >> 4;
    #pragma unroll
    for (int ks = 0; ks < 64; ks += 32) {
        const int kg = ks + lg * 8;
        bf16x8 bh8[5], bl8[5];
        #pragma unroll
        for (int n = 0; n < 5; ++n) {
            float bv[8];
            #pragma unroll
            for (int j = 0; j < 8; ++j) bv[j] = u.s.Cm[n * 16 + lr][kg + j];
            cvt8(bv, bh8[n], bl8[n]);
        }
        #pragma unroll
        for (int m = 0; m < 2; ++m) {
            float av[8];
            const int row = w * 32 + m * 16 + lr;
            #pragma unroll
            for (int j = 0; j < 8; ++j) av[j] = u.s.Emb[row][kg + j];
            bf16x8 ah8, al8;
            cvt8(av, ah8, al8);
            #pragma unroll
            for (int n = 0; n < 5; ++n) {
                acc[m][n] = __builtin_amdgcn_mfma_f32_16x16x32_bf16(ah8, bh8[n], acc[m][n], 0, 0, 0);
                acc[m][n] = __builtin_amdgcn_mfma_f32_16x16x32_bf16(ah8, bl8[n], acc[m][n], 0, 0, 0);
                acc[m][n] = __builtin_amdgcn_mfma_f32_16x16x32_bf16(al8, bh8[n], acc[m][n], 0, 0, 0);
            }
        }
    }
    __syncthreads();
    #pragma unroll
    for (int n = 0; n < 5; ++n) {
        int c = n * 16 + lr;
        if (c < 66) {
            #pragma unroll
            for (int m = 0; m < 2; ++m)
                #pragma unroll
                for (int j = 0; j < 4; ++j)
                    u.Dl[c][w * 32 + m * 16 + lg * 4 + j] = acc[m][n][j];
        }
    }
    __syncthreads();
    for (int i = tid; i < 66 * 128; i += 256) {
        int c = i >> 7, t = i & 127;
        float val = u.Dl[c][t];
        if (c < 33) XcRe[(size_t)(bh * NF + c) * SL + t0 + t] = val;
        else        XcIm[(size_t)(bh * NF + (c - 33)) * SL + t0 + t] = val;
    }
}

// K5: Stockham fwd FFT -> pointwise * Pf -> Stockham inv FFT, in-place on Xc planes.
__global__ __launch_bounds__(256) void k5_seq_conv(float* __restrict__ XcRe, float* __restrict__ XcIm,
                                                   const float2* __restrict__ Pf,
                                                   const float2* __restrict__ twg) {
    __shared__ float Ar[2304], Ai[2304], Br[2304], Bi[2304];
    __shared__ float2 twd[512];
    int f = blockIdx.x % NF;
    int bh = blockIdx.x / NF;
    int h = bh % NH;
    int tid = threadIdx.x;
    for (int i = tid; i < 512; i += 256) twd[i] = twg[i];
    float* xre = XcRe + (size_t)(bh * NF + f) * SL;
    float* xim = XcIm + (size_t)(bh * NF + f) * SL;
    {
        float2 v[8];
        #pragma unroll
        for (int r = 0; r < 4; ++r) v[r] = make_float2(xre[tid + 256 * r], xim[tid + 256 * r]);
        #pragma unroll
        for (int r = 4; r < 8; ++r) v[r] = make_float2(0.f, 0.f);
        dft8v<-1>(v);
        #pragma unroll
        for (int r = 0; r < 8; ++r) {
            int idx = FPAD(tid * 8 + r);
            Ar[idx] = v[r].x; Ai[idx] = v[r].y;
        }
    }
    __syncthreads();
    fft_stage<-1, 8, 8>(Ar, Ai, Br, Bi, twd, tid);   __syncthreads();
    fft_stage<-1, 64, 8>(Br, Bi, Ar, Ai, twd, tid);  __syncthreads();
    fft_stage<-1, 512, 4>(Ar, Ai, Br, Bi, twd, tid); __syncthreads();
    const float2* pf = Pf + (size_t)(h * NF + f) * NSEQ;
    #pragma unroll
    for (int q = 0; q < 8; ++q) {
        int i = tid + 256 * q;
        int idx = FPAD(i);
        float2 a = make_float2(Br[idx], Bi[idx]);
        float2 p = cmul(a, pf[i]);
        Br[idx] = p.x; Bi[idx] = p.y;
    }
    __syncthreads();
    fft_stage<1, 1, 8>(Br, Bi, Ar, Ai, twd, tid);  __syncthreads();
    fft_stage<1, 8, 8>(Ar, Ai, Br, Bi, twd, tid);  __syncthreads();
    fft_stage<1, 64, 8>(Br, Bi, Ar, Ai, twd, tid); __syncthreads();
    const float sc = 1.0f / 2048.0f;
    #pragma unroll
    for (int jj = 0; jj < 512; jj += 256) {
        int j = tid + jj;
        float2 v[4];
        #pragma unroll
        for (int r = 0; r < 4; ++r) {
            int idx = FPAD(j + 512 * r);
            v[r] = make_float2(Ar[idx], Ai[idx]);
        }
        float2 w1 = twd[j];
        w1.y = -w1.y;
        float2 w = w1;
        v[1] = cmul(v[1], w);
        w = cmul(w, w1); v[2] = cmul(v[2], w);
        w = cmul(w, w1); v[3] = cmul(v[3], w);
        dft4v<1>(v);
        xre[j] = v[0].x * sc;        xim[j] = v[0].y * sc;
        xre[j + 512] = v[1].x * sc;  xim[j + 512] = v[1].y * sc;
    }
}

// K6m: inverse channel DFT-64 as split-bf16 MFMA + exact GELU.
__global__ __launch_bounds__(256) void k6_mfma(const float* __restrict__ XcRe,
                                               const float* __restrict__ XcIm,
                                               ushort* __restrict__ Gh, ushort* __restrict__ Gl) {
    __shared__ float Ys[64][133];
    __shared__ float Cm[64][65];
    const int t0 = blockIdx.x * 128;
    const int bh = blockIdx.y;
    const int b = bh / NH, h = bh % NH;
    const int tid = threadIdx.x, lane = tid & 63, w = tid >> 6;

    for (int i = tid; i < 64 * 32; i += 256) {
        int c = i >> 5, tq = i & 31;
        const float* src = (c < 33) ? XcRe + (size_t)(bh * NF + c) * SL
                                    : XcIm + (size_t)(bh * NF + (c - 32)) * SL;
        float4 v = *(const float4*)&src[t0 + tq * 4];
        Ys[c][tq * 4 + 0] = v.x; Ys[c][tq * 4 + 1] = v.y;
        Ys[c][tq * 4 + 2] = v.z; Ys[c][tq * 4 + 3] = v.w;
    }
    for (int i = tid; i < 64 * 64; i += 256) {
        int e = i >> 6, c = i & 63;
        float v;
        if (c <= 32) {
            int m = (c * e) & 63;
            float wt = (c == 0 || c == 32) ? (1.0f / 64.0f) : (2.0f / 64.0f);
            v = wt * cosf(0.09817477042468103870f * (float)m);
        } else {
            int m = ((c - 32) * e) & 63;
            v = -(2.0f / 64.0f) * sinf(0.09817477042468103870f * (float)m);
        }
        Cm[e][c] = v;
    }
    __syncthreads();

    f32x4 acc[2][4] = {};
    const int lr = lane & 15, lg = lane >> 4;
    #pragma unroll
    for (int ks = 0; ks < 64; ks += 32) {
        const int kg = ks + lg * 8;
        bf16x8 bh8[4], bl8[4];
        #pragma unroll
        for (int n = 0; n < 4; ++n) {
            float bv[8];
            #pragma unroll
            for (int j = 0; j < 8; ++j) bv[j] = Cm[n * 16 + lr][kg + j];
            cvt8(bv, bh8[n], bl8[n]);
        }
        #pragma unroll
        for (int m = 0; m < 2; ++m) {
            const int row = w * 32 + m * 16 + lr;
            float av[8];
            #pragma unroll
            for (int j = 0; j < 8; ++j) av[j] = Ys[kg + j][row];
            bf16x8 ah8, al8;
            cvt8(av, ah8, al8);
            #pragma unroll
            for (int n = 0; n < 4; ++n) {
                acc[m][n] = __builtin_amdgcn_mfma_f32_16x16x32_bf16(ah8, bh8[n], acc[m][n], 0, 0, 0);
                acc[m][n] = __builtin_amdgcn_mfma_f32_16x16x32_bf16(ah8, bl8[n], acc[m][n], 0, 0, 0);
                acc[m][n] = __builtin_amdgcn_mfma_f32_16x16x32_bf16(al8, bh8[n], acc[m][n], 0, 0, 0);
            }
        }
    }
    #pragma unroll
    for (int n = 0; n < 4; ++n) {
        const int col = h * 64 + n * 16 + lr;
        #pragma unroll
        for (int m = 0; m < 2; ++m) {
            #pragma unroll
            for (int j = 0; j < 4; ++j) {
                int t = t0 + w * 32 + m * 16 + lg * 4 + j;
                float v = acc[m][n][j];
                float g = 0.5f * v * (1.0f + erff(v * 0.70710678118654752440f));
                size_t idx = ((size_t)b * SL + t) * ED + col;
                unsigned short hb = bf16bits(g);
                Gh[idx] = hb;
                Gl[idx] = bf16bits(g - bf16val(hb));
            }
        }
    }
}

// K0b: cast W to bf16 hi/lo pair.
__global__ void k0_castW(const float* __restrict__ W,
                         ushort* __restrict__ Wh, ushort* __restrict__ Wl) {
    int i = blockIdx.x * 256 + threadIdx.x;
    if (i < ED * ED) {
        float w = W[i];
        unsigned short hb = bf16bits(w);
        Wh[i] = hb;
        Wl[i] = bf16bits(w - bf16val(hb));
    }
}

// K7: projection GEMM via split-bf16 MFMA.
__global__ __launch_bounds__(256) void k7_mfma(
        const ushort* __restrict__ Gh, const ushort* __restrict__ Gl,
        const ushort* __restrict__ Wh, const ushort* __restrict__ Wl,
        const float* __restrict__ bias, float* __restrict__ out) {
    __shared__ ushort Ah[128 * 32], Al[128 * 32], Bh[128 * 32], Bl[128 * 32];
    const int j0 = blockIdx.x * 128;
    const int i0 = blockIdx.y * 128;
    const int tid = threadIdx.x;
    const int lane = tid & 63, wid = tid >> 6;
    const int wm = wid >> 1, wn = wid & 1;

    const int stRow = wid * 32 + (lane >> 2);
    const int stCol = (lane & 3) * 8;
    const int ldsBase0 = wid * 1024;
    const int ldsBase1 = wid * 1024 + 512;

    f32x4 acc[4][4] = {};

    const int arow = wm * 64 + (lane & 15);
    const int brow = wn * 64 + (lane & 15);
    const int kb8  = (lane >> 4) * 8;

    for (int k0 = 0; k0 < ED; k0 += 32) {
        const ushort* gA = Gh + (size_t)(i0 + stRow) * ED + k0 + stCol;
        const ushort* gAl = Gl + (size_t)(i0 + stRow) * ED + k0 + stCol;
        const ushort* gB = Wh + (size_t)(j0 + stRow) * ED + k0 + stCol;
        const ushort* gBl = Wl + (size_t)(j0 + stRow) * ED + k0 + stCol;
        __builtin_amdgcn_global_load_lds(GLB_U32(gA), LDS_U32(&Ah[ldsBase0]), 16, 0, 0);
        __builtin_amdgcn_global_load_lds(GLB_U32(gA + 16 * ED), LDS_U32(&Ah[ldsBase1]), 16, 0, 0);
        __builtin_amdgcn_global_load_lds(GLB_U32(gAl), LDS_U32(&Al[ldsBase0]), 16, 0, 0);
        __builtin_amdgcn_global_load_lds(GLB_U32(gAl + 16 * ED), LDS_U32(&Al[ldsBase1]), 16, 0, 0);
        __builtin_amdgcn_global_load_lds(GLB_U32(gB), LDS_U32(&Bh[ldsBase0]), 16, 0, 0);
        __builtin_amdgcn_global_load_lds(GLB_U32(gB + 16 * ED), LDS_U32(&Bh[ldsBase1]), 16, 0, 0);
        __builtin_amdgcn_global_load_lds(GLB_U32(gBl), LDS_U32(&Bl[ldsBase0]), 16, 0, 0);
        __builtin_amdgcn_global_load_lds(GLB_U32(gBl + 16 * ED), LDS_U32(&Bl[ldsBase1]), 16, 0, 0);
        __syncthreads();

        bf16x8 ah[4], al[4], bh[4], bl[4];
        #pragma unroll
        for (int m = 0; m < 4; ++m) {
            ah[m] = *(const bf16x8*)&Ah[(arow + m * 16) * 32 + kb8];
            al[m] = *(const bf16x8*)&Al[(arow + m * 16) * 32 + kb8];
        }
        #pragma unroll
        for (int n = 0; n < 4; ++n) {
            bh[n] = *(const bf16x8*)&Bh[(brow + n * 16) * 32 + kb8];
            bl[n] = *(const bf16x8*)&Bl[(brow + n * 16) * 32 + kb8];
        }
        #pragma unroll
        for (int m = 0; m < 4; ++m)
            #pragma unroll
            for (int n = 0; n < 4; ++n) {
                acc[m][n] = __builtin_amdgcn_mfma_f32_16x16x32_bf16(ah[m], bh[n], acc[m][n], 0, 0, 0);
                acc[m][n] = __builtin_amdgcn_mfma_f32_16x16x32_bf16(ah[m], bl[n], acc[m][n], 0, 0, 0);
                acc[m][n] = __builtin_amdgcn_mfma_f32_16x16x32_bf16(al[m], bh[n], acc[m][n], 0, 0, 0);
            }
        __syncthreads();
    }

    const int ocol0 = j0 + wn * 64 + (lane & 15);
    const int orow0 = i0 + wm * 64 + (lane >> 4) * 4;
    #pragma unroll
    for (int n = 0; n < 4; ++n) {
        const float bv = bias[ocol0 + n * 16];
        #pragma unroll
        for (int m = 0; m < 4; ++m) {
            #pragma unroll
            for (int j = 0; j < 4; ++j) {
                out[(size_t)(orow0 + m * 16 + j) * ED + ocol0 + n * 16] = acc[m][n][j] + bv;
            }
        }
    }
}

extern "C" void kernel_launch(void* const* d_in, const int* in_sizes, int n_in,
                              void* d_out, int out_size, void* d_ws, size_t ws_size,
                              hipStream_t stream) {
    (void)in_sizes; (void)n_in; (void)out_size; (void)ws_size;
    const float* emb  = (const float*)d_in[0];   // [8,1024,768]
    const float* tp   = (const float*)d_in[1];   // [12,2047,64]
    const float* W    = (const float*)d_in[2];   // [768,768]
    const float* bias = (const float*)d_in[3];   // [768]

    float* out_conv = (float*)d_out;                             // 8*1024*768
    float* out_psf  = out_conv + (size_t)NB * SL * ED;           // 12*2047*64

    // workspace layout:
    float2* Pc = (float2*)d_ws;                                  // 12*33*1024 complex (dead after k3)
    float2* Pf = Pc + (size_t)NH * NF * SL;                      // 12*33*2048 complex
    float*  XcRe = (float*)(Pf + (size_t)NH * NF * NSEQ);        // 96*33*1024 f32
    float*  XcIm = XcRe + (size_t)NB * NH * NF * SL;             // 96*33*1024 f32
    ushort* Gh = (ushort*)(XcIm + (size_t)NB * NH * NF * SL);    // 8192*768 bf16
    ushort* Gl = Gh + (size_t)NB * SL * ED;                      // 8192*768 bf16
    // W hi/lo overlaid on Pc region (2.36 MB <= 3.24 MB), written after k3 consumes Pc
    ushort* Whh = (ushort*)Pc;
    ushort* Wll = Whh + (size_t)ED * ED;
    // twiddle table overlaid on Gh start (4 KB): consumed by k3/k5 before k6 writes Gh
    float2* twg = (float2*)Gh;
    // softmax partials overlaid on Pf start (dead until k3 writes Pf)
    float* pMax = (float*)Pf;          // 12*32*64
    float* pSum = pMax + NH * 32 * 64; // 12*32*64
    float* Mf   = pSum + NH * 32 * 64; // 768
    float* Invf = Mf + NH * 64;        // 768

    ktw<<<dim3(2), dim3(256), 0, stream>>>(twg);
    k1a_partial<<<dim3(32, NH), dim3(256), 0, stream>>>(tp, pMax, pSum);
    k1b_fold<<<dim3(NH), dim3(64), 0, stream>>>(pMax, pSum, Mf, Invf);
    k1c_norm<<<dim3(32, NH), dim3(256), 0, stream>>>(tp, Mf, Invf, out_psf);
    k2_psf_cdft<<<dim3(SL / 64, NH), dim3(256), 0, stream>>>(out_psf, Pc);
    k3_psf_fft<<<dim3(NH * NF), dim3(256), 0, stream>>>(Pc, Pf, twg);
    k0_castW<<<dim3((ED * ED + 255) / 256), dim3(256), 0, stream>>>(W, Whh, Wll);
    k4_mfma<<<dim3(SL / 128, NB * NH), dim3(256), 0, stream>>>(emb, XcRe, XcIm);
    k5_seq_conv<<<dim3(NB * NH * NF), dim3(256), 0, stream>>>(XcRe, XcIm, Pf, twg);
    k6_mfma<<<dim3(SL / 128, NB * NH), dim3(256), 0, stream>>>(XcRe, XcIm, Gh, Gl);
    k7_mfma<<<dim3(ED / 128, (NB * SL) / 128), dim3(256), 0, stream>>>(
        Gh, Gl, Whh, Wll, bias, out_conv);
}